// Round 6
// baseline (366.020 us; speedup 1.0000x reference)
//
#include <hip/hip_runtime.h>

typedef float floatx4 __attribute__((ext_vector_type(4)));
typedef __bf16 bf16x8 __attribute__((ext_vector_type(8)));
using u16 = unsigned short;
using u32 = unsigned int;

#define GLOBAL_AS __attribute__((address_space(1)))
#define LDS_AS    __attribute__((address_space(3)))

// ---------------- conversion: x fp32 -> bf16 (RNE), row-major ----------------
__global__ void cvt_x_kernel(const float* __restrict__ x, u16* __restrict__ xb, int n8) {
  int stride = gridDim.x * blockDim.x;
  for (int i = blockIdx.x * blockDim.x + threadIdx.x; i < n8; i += stride) {
    const float4* p = (const float4*)(x + (size_t)i * 8);
    float4 a = p[0], b = p[1];
    float v[8] = {a.x, a.y, a.z, a.w, b.x, b.y, b.z, b.w};
    u32 r[8];
#pragma unroll
    for (int j = 0; j < 8; ++j) {
      u32 u = __float_as_uint(v[j]);
      r[j] = (u + 0x7FFFu + ((u >> 16) & 1u)) >> 16;  // RNE
    }
    uint4 o;
    o.x = r[0] | (r[1] << 16);
    o.y = r[2] | (r[3] << 16);
    o.z = r[4] | (r[5] << 16);
    o.w = r[6] | (r[7] << 16);
    *(uint4*)(xb + (size_t)i * 8) = o;
  }
}

// ------- quantize W -> ternary bf16 AND scatter into MFMA-fragment order -------
// Per bn-panel (256 rows), per K64-tile: u16 offset =
//   bnp*256*K + tile*16384 + wcg*4096 + f*512 + l*8 + ko
// where n = bnp*256 + wcg*64 + ng*16 + r; k = tile*64 + j*32 + g*8 + ko;
// f = ng*2 + j; l = g*16 + r.  A wave's frag load is then base + f*512 + lane*8
// -> one coalesced 1KB global_load_dwordx4 per fragment.
__global__ void quant_w_perm(const float* __restrict__ w, u16* __restrict__ wb,
                             int K, int Kd8, int n8) {
  int stride = gridDim.x * blockDim.x;
  for (int i = blockIdx.x * blockDim.x + threadIdx.x; i < n8; i += stride) {
    const int n = i / Kd8;
    const int k = (i - n * Kd8) * 8;
    const float4* p = (const float4*)(w + (size_t)n * K + k);
    float4 a = p[0], b = p[1];
    float v[8] = {a.x, a.y, a.z, a.w, b.x, b.y, b.z, b.w};
    u32 r[8];
#pragma unroll
    for (int j = 0; j < 8; ++j) {
      r[j] = (v[j] > 0.05f) ? 0x3F80u : ((v[j] < -0.05f) ? 0xBF80u : 0u);
    }
    uint4 o;
    o.x = r[0] | (r[1] << 16);
    o.y = r[2] | (r[3] << 16);
    o.z = r[4] | (r[5] << 16);
    o.w = r[6] | (r[7] << 16);
    const int bnp = n >> 8, nl = n & 255;
    const int wcg = nl >> 6, ng = (nl >> 4) & 3, rr = nl & 15;
    const int tile = k >> 6, jj = (k >> 5) & 1, g = (k >> 3) & 3;
    const int f = ng * 2 + jj, l = g * 16 + rr;
    u16* dst = wb + (size_t)bnp * 256 * K + tile * 16384 + wcg * 4096 + f * 512 + l * 8;
    *(uint4*)dst = o;
  }
}

// ---------------- 256x256 bf16 GEMM: A in LDS (ring-2), B direct-to-reg ----------------
// out[m][n] = sum_k A[m][k]*B[n][k] + bias[n]. 8 waves (2x4), per-wave 128x64.
// LDS 64 KB: 2 buffers x 16384 u16, fragment-ordered A (frag fi=mg*2+j at
// half*8192 + fi*512 + l*8; staged linearly by global_load_lds from permuted src).
// Per tile: issue A-stage(t+1) (4 gload_lds) + B(t+1) (8 reg loads, ping-pong),
// then 4 MFMA quadrants with af m0/m1 read 8+8 from LDS; ONE barrier per tile;
// manual vmcnt(8) drains only the A-stage (B waits are compiler-counted).
// Waves free-run within a tile -> cross-wave LDS/MFMA overlap.
__global__ __launch_bounds__(512, 2) void gemm_bdir(
    const u16* __restrict__ A, const u16* __restrict__ Bp,
    const float* __restrict__ bias, float* __restrict__ C,
    int M, int N, int K) {
  __shared__ u16 lds[32768];  // 64 KiB

  const int tid = threadIdx.x;
  const int w = tid >> 6, l = tid & 63;
  const int wr = w >> 2, wc = w & 3;
  const int r = l & 15;

  const int nbn = N >> 8;
  int wg = blockIdx.x;
  const int nwg = gridDim.x;
  if ((nwg & 7) == 0) wg = (wg & 7) * (nwg >> 3) + (wg >> 3);  // XCD swizzle
  const int bm = wg / nbn, bn = wg % nbn;

  const int T = K >> 6;

  // A staging: gload c covers buffer elems c*4096 + tid*8 (linear dest);
  // source is the fragment-permuted global address.
  const u16* Asrc[4];
#pragma unroll
  for (int c = 0; c < 4; ++c) {
    const int e = c * 4096 + tid * 8;
    const int half = e >> 13, fi = (e >> 9) & 15, ll = (e >> 3) & 63;
    const int mg = fi >> 1, j = fi & 1, g = ll >> 4, rr2 = ll & 15;
    const int row = bm * 256 + half * 128 + mg * 16 + rr2;
    Asrc[c] = A + (size_t)row * K + j * 32 + g * 8;
  }
  // B fragment base for this wave: + t*16384 per tile, + f*512 per frag
  const u16* const Bbase = Bp + (size_t)bn * 256 * K + wc * 4096 + l * 8;
  const u16* const ldsA = lds + wr * 8192 + l * 8;

  floatx4 acc[8][4] = {};
  bf16x8 af[8], BAs[8], BBs[8];

#define AST(tt, bufoff)                                                        \
  {                                                                            \
    _Pragma("unroll")                                                          \
    for (int c = 0; c < 4; ++c)                                                \
      __builtin_amdgcn_global_load_lds(                                        \
          (const GLOBAL_AS void*)(Asrc[c] + (size_t)(tt) * 64),                \
          (LDS_AS void*)(lds + (bufoff) + c * 4096 + tid * 8), 16, 0, 0);      \
  }
#define BLD(tt, DST)                                                           \
  {                                                                            \
    _Pragma("unroll")                                                          \
    for (int f = 0; f < 8; ++f)                                                \
      DST[f] = *(const bf16x8*)(Bbase + (size_t)(tt) * 16384 + f * 512);       \
  }

  // prologue: A(0)->buf0, B(0)->BAs
  AST(0, 0);
  BLD(0, BAs);
  asm volatile("s_waitcnt vmcnt(8)" ::: "memory");  // A(0) landed (B still in flight)
  __builtin_amdgcn_s_barrier();

#define MFMA_Q(MGOFF, NGOFF, CUR)                                              \
  __builtin_amdgcn_s_setprio(1);                                               \
  _Pragma("unroll")                                                            \
  for (int mg = 0; mg < 4; ++mg)                                               \
    _Pragma("unroll")                                                          \
    for (int ng = 0; ng < 2; ++ng)                                             \
      _Pragma("unroll")                                                        \
      for (int j = 0; j < 2; ++j)                                              \
        acc[(MGOFF) + mg][(NGOFF) + ng] =                                      \
            __builtin_amdgcn_mfma_f32_16x16x32_bf16(                           \
                af[mg * 2 + j], CUR[(NGOFF) * 2 + ng * 2 + j],                 \
                acc[(MGOFF) + mg][(NGOFF) + ng], 0, 0, 0);                     \
  __builtin_amdgcn_s_setprio(0);

#define TILE(t, CUR, NXT, DOST)                                                \
  {                                                                            \
    const int buf_ = ((t) & 1) * 16384;                                        \
    if (DOST) {                                                                \
      AST((t) + 1, buf_ ^ 16384);                                              \
      BLD((t) + 1, NXT);                                                       \
    }                                                                          \
    /* P1: af m0 (frags 0..7) */                                               \
    _Pragma("unroll")                                                          \
    for (int fi = 0; fi < 8; ++fi)                                             \
      af[fi] = *(const bf16x8*)(ldsA + buf_ + fi * 512);                       \
    asm volatile("s_waitcnt lgkmcnt(0)" ::: "memory");                         \
    __builtin_amdgcn_sched_barrier(0);                                         \
    MFMA_Q(0, 0, CUR)                                                          \
    /* P2 */                                                                   \
    MFMA_Q(0, 2, CUR)                                                          \
    /* P3: af m1 (frags 8..15) */                                              \
    _Pragma("unroll")                                                          \
    for (int fi = 0; fi < 8; ++fi)                                             \
      af[fi] = *(const bf16x8*)(ldsA + buf_ + 4096 + fi * 512);                \
    asm volatile("s_waitcnt lgkmcnt(0)" ::: "memory");                         \
    __builtin_amdgcn_sched_barrier(0);                                         \
    MFMA_Q(4, 0, CUR)                                                          \
    /* P4 */                                                                   \
    MFMA_Q(4, 2, CUR)                                                          \
    if (DOST) {                                                                \
      asm volatile("s_waitcnt vmcnt(8)" ::: "memory"); /* drain A-stage only */ \
      __builtin_amdgcn_s_barrier();                                            \
    }                                                                          \
  }

  for (int t2 = 0; t2 < T - 2; t2 += 2) {
    TILE(t2,     BAs, BBs, true);
    TILE(t2 + 1, BBs, BAs, true);
  }
  TILE(T - 2, BAs, BBs, true);
  TILE(T - 1, BBs, BAs, false);
#undef TILE
#undef MFMA_Q
#undef AST
#undef BLD

  // ---- epilogue: C/D layout col = l&15, row = (l>>4)*4 + q ----
  const int g = l >> 4;
  const int colb = bn * 256 + wc * 64;
  float bv[4];
#pragma unroll
  for (int n = 0; n < 4; ++n) bv[n] = bias[colb + n * 16 + r];
  const int rowb0 = bm * 256 + wr * 128;
#pragma unroll
  for (int m = 0; m < 8; ++m) {
    const int rowb = rowb0 + m * 16 + g * 4;
#pragma unroll
    for (int n = 0; n < 4; ++n) {
      const int col = colb + n * 16 + r;
      float* cp = C + (size_t)rowb * N + col;
#pragma unroll
      for (int q = 0; q < 4; ++q) cp[(size_t)q * N] = acc[m][n][q] + bv[n];
    }
  }
}

// ---------------- fallback: slow but correct ----------------
__global__ void gemm_naive_kernel(const float* __restrict__ x, const float* __restrict__ wgt,
                                  const float* __restrict__ bias, float* __restrict__ out,
                                  int M, int N, int K) {
  long long idx = (long long)blockIdx.x * blockDim.x + threadIdx.x;
  if (idx >= (long long)M * N) return;
  int o = (int)(idx % N);
  int m = (int)(idx / N);
  const float* xr = x + (size_t)m * K;
  const float* wr = wgt + (size_t)o * K;
  float s = 0.f;
  for (int i = 0; i < K; ++i) {
    float wv = wr[i];
    float t = (wv > 0.05f) ? 1.f : ((wv < -0.05f) ? -1.f : 0.f);
    s = fmaf(xr[i], t, s);
  }
  out[idx] = s + bias[o];
}

extern "C" void kernel_launch(void* const* d_in, const int* in_sizes, int n_in,
                              void* d_out, int out_size, void* d_ws, size_t ws_size,
                              hipStream_t stream) {
  const float* x    = (const float*)d_in[0];
  const float* wgt  = (const float*)d_in[1];
  const float* bias = (const float*)d_in[2];
  float* out = (float*)d_out;

  const int N = in_sizes[2];                 // out features
  const int K = in_sizes[1] / N;             // in features
  const int M = in_sizes[0] / K;             // batch rows

  const size_t need = ((size_t)M * K + (size_t)N * K) * sizeof(u16);
  if (ws_size >= need && (M % 256 == 0) && (N % 256 == 0) && (K % 64 == 0) && K >= 256) {
    u16* xb = (u16*)d_ws;
    u16* wb = xb + (size_t)M * K;
    const int nx8 = (M * K) / 8;
    const int nw8 = (N * K) / 8;
    cvt_x_kernel<<<2048, 256, 0, stream>>>(x, xb, nx8);
    quant_w_perm<<<2048, 256, 0, stream>>>(wgt, wb, K, K / 8, nw8);
    const int grid = (M / 256) * (N / 256);
    gemm_bdir<<<grid, 512, 0, stream>>>(xb, wb, bias, out, M, N, K);
  } else {
    const long long total = (long long)M * N;
    gemm_naive_kernel<<<(unsigned)((total + 255) / 256), 256, 0, stream>>>(x, wgt, bias, out, M, N, K);
  }
}